// Round 11
// baseline (528.331 us; speedup 1.0000x reference)
//
#include <hip/hip_runtime.h>

#define NN 50000
#define NE 800000
#define HH 128
#define SCAN_BLK 256
#define NBLK ((NN + SCAN_BLK - 1) / SCAN_BLK)   // 196
#define NB8 ((NN + 7) / 8)                      // 6250 (8 nodes/block)
#define NPT 6250                                // nodes per XCD team
#define TSB 128                                 // stripes per team
#define ECH ((NE + TSB - 1) / TSB)              // edges per stripe

typedef _Float16 half8 __attribute__((ext_vector_type(8)));
typedef _Float16 half4 __attribute__((ext_vector_type(4)));
typedef float floatx16 __attribute__((ext_vector_type(16)));

static inline size_t align256(size_t x) { return (x + 255) & ~(size_t)255; }

// ---------------- degree histogram, XCD-pinned teams, nt streaming reads ----------------
__global__ __launch_bounds__(256) void k_deg(const int* __restrict__ dst,
                                             int* __restrict__ deg) {
    const int c = blockIdx.x & 7;
    const int stripe = blockIdx.x >> 3;
    const int lo = c * NPT, hi = min(NN, lo + NPT);
    const int e0 = stripe * ECH;
    const int e1 = min(NE, e0 + ECH);
    for (int e = e0 + threadIdx.x; e < e1; e += 256) {
        int d = __builtin_nontemporal_load(dst + e);
        if (d >= lo && d < hi) atomicAdd(&deg[d], 1);
    }
}

// ---------------- two-level scan ----------------
__global__ void k_bsum(const int* __restrict__ deg, int* __restrict__ part) {
    __shared__ int sd[SCAN_BLK];
    int t = threadIdx.x;
    int i = blockIdx.x * SCAN_BLK + t;
    sd[t] = (i < NN) ? deg[i] : 0;
    __syncthreads();
    for (int off = SCAN_BLK / 2; off > 0; off >>= 1) {
        if (t < off) sd[t] += sd[t + off];
        __syncthreads();
    }
    if (t == 0) part[blockIdx.x] = sd[0];
}

__global__ void k_scanpart(const int* __restrict__ part, int* __restrict__ partoff) {
    __shared__ int sd[SCAN_BLK];
    int t = threadIdx.x;
    int v = (t < NBLK) ? part[t] : 0;
    sd[t] = v;
    __syncthreads();
    for (int off = 1; off < SCAN_BLK; off <<= 1) {
        int add = (t >= off) ? sd[t - off] : 0;
        __syncthreads();
        sd[t] += add;
        __syncthreads();
    }
    if (t < NBLK) partoff[t] = sd[t] - v;
}

__global__ void k_apply(const int* __restrict__ deg, const int* __restrict__ partoff,
                        int* __restrict__ offsets, float* __restrict__ dinv) {
    __shared__ int sd[SCAN_BLK];
    int t = threadIdx.x;
    int i = blockIdx.x * SCAN_BLK + t;
    int v = (i < NN) ? deg[i] : 0;
    sd[t] = v;
    __syncthreads();
    for (int off = 1; off < SCAN_BLK; off <<= 1) {
        int add = (t >= off) ? sd[t - off] : 0;
        __syncthreads();
        sd[t] += add;
        __syncthreads();
    }
    if (i < NN) {
        offsets[i] = partoff[blockIdx.x] + sd[t] - v;
        dinv[i] = (v > 0) ? rsqrtf((float)v) : 0.0f;
    }
    if (i == 0) offsets[NN] = NE;
}

// ---------------- CSR fill, XCD-pinned teams, nt streaming reads ----------------
__global__ __launch_bounds__(256) void k_fill(const int* __restrict__ src,
                                              const int* __restrict__ dst,
                                              const int* __restrict__ offsets,
                                              int* __restrict__ cursor,
                                              int* __restrict__ csrc) {
    const int c = blockIdx.x & 7;
    const int stripe = blockIdx.x >> 3;
    const int lo = c * NPT, hi = min(NN, lo + NPT);
    const int e0 = stripe * ECH;
    const int e1 = min(NE, e0 + ECH);
    for (int e = e0 + threadIdx.x; e < e1; e += 256) {
        int d = __builtin_nontemporal_load(dst + e);
        if (d >= lo && d < hi) {
            int s = __builtin_nontemporal_load(src + e);
            int pos = atomicAdd(&cursor[d], 1);
            csrc[offsets[d] + pos] = s;
        }
    }
}

// ---------------- convert x to fp16 ----------------
__global__ void k_cvt_x(const float* __restrict__ x, _Float16* __restrict__ xh) {
    int i = blockIdx.x * 256 + threadIdx.x;
    if (i * 4 < NN * HH) {
        float4 v = *(const float4*)(x + (size_t)i * 4);
        half4 h;
        h.x = (_Float16)v.x; h.y = (_Float16)v.y;
        h.z = (_Float16)v.z; h.w = (_Float16)v.w;
        *(half4*)(xh + (size_t)i * 4) = h;
    }
}

// ---------------- convert + transpose weights to fp16 k-major ----------------
// W1t256[c][k]: c<128 -> W1[k][c] (P); c>=128 -> W1[128+k][c-128] (Q). bias256=[b1|0].
__global__ void k_cvt_w(const float* __restrict__ W1, const float* __restrict__ W2,
                        const float* __restrict__ tw, const float* __restrict__ b1,
                        _Float16* __restrict__ W1t256, float* __restrict__ bias256,
                        _Float16* __restrict__ W2t, _Float16* __restrict__ TWt,
                        int* __restrict__ deg, int* __restrict__ cursor) {
    int i = blockIdx.x * 256 + threadIdx.x;
    if (i < 32768) {
        int c = i >> 7, k = i & 127;
        W1t256[c * 128 + k] = (c < 128) ? (_Float16)W1[k * 128 + c]
                                        : (_Float16)W1[(128 + k) * 128 + (c - 128)];
    } else if (i < 49152) {
        int j = i - 32768;
        int c = j >> 7, k = j & 127;
        W2t[c * 128 + k] = (_Float16)W2[k * 128 + c];
    } else if (i < 49152 + 3 * 65536) {
        int j = i - 49152;
        int L = j >> 16;
        int c = (j >> 9) & 127;
        int k = j & 511;
        TWt[(size_t)L * 65536 + c * 512 + k] =
            (_Float16)tw[(size_t)L * 65536 + (size_t)(k >> 7) * 16384 + (size_t)(k & 127) * 128 + c];
    } else {
        int j = i - (49152 + 3 * 65536);
        if (j < 256) bias256[j] = (j < 128) ? b1[j] : 0.0f;
        // zero deg + cursor (replaces two hipMemsetAsync)
        int z = j - 256;
        if (z >= 0 && z < NN) { deg[z] = 0; cursor[z] = 0; }
    }
}

// ---------------- MFMA GEMM (col-tiled via blockIdx.y) ----------------
template <int KDIM, int HAS_BIAS, int HAS_DEG, int RELU, typename OutT>
__global__ __launch_bounds__(256) void k_mm(
    const _Float16* __restrict__ A, int lda,
    const _Float16* __restrict__ Bt,
    const float* __restrict__ bias, const int* __restrict__ deg,
    OutT* __restrict__ Out, int ldo, int nrows) {
    __shared__ _Float16 As[128 * 64];
    __shared__ _Float16 Bs[128 * 64];
    const int t = threadIdx.x;
    const int l = t & 63;
    const int w = t >> 6;
    const int wm = w >> 1, wn = w & 1;
    const int row0 = blockIdx.x * 128;
    const int col0 = blockIdx.y * 128;
    const _Float16* BtT = Bt + (size_t)col0 * KDIM;

    floatx16 acc[2][2] = {};

    const int srow = t >> 3;
    const int sslot = t & 7;

    for (int c = 0; c < KDIM / 64; ++c) {
        __syncthreads();
#pragma unroll
        for (int p = 0; p < 4; ++p) {
            int r = srow + p * 32;
            int g = row0 + r;
            uint4 v = make_uint4(0, 0, 0, 0);
            if (g < nrows) v = *(const uint4*)(A + (size_t)g * lda + c * 64 + sslot * 8);
            *(uint4*)((char*)As + r * 128 + ((sslot * 16) ^ ((r & 7) << 4))) = v;
        }
#pragma unroll
        for (int p = 0; p < 4; ++p) {
            int r = srow + p * 32;
            uint4 v = *(const uint4*)(BtT + (size_t)r * KDIM + c * 64 + sslot * 8);
            *(uint4*)((char*)Bs + r * 128 + ((sslot * 16) ^ ((r & 7) << 4))) = v;
        }
        __syncthreads();
#pragma unroll
        for (int ks = 0; ks < 4; ++ks) {
            const int koff = ks * 32 + (l >> 5) * 16;
            half8 a0, a1, b0, b1;
            { int r = wm * 64 + (l & 31);      a0 = *(const half8*)((const char*)As + r * 128 + (koff ^ ((r & 7) << 4))); }
            { int r = wm * 64 + 32 + (l & 31); a1 = *(const half8*)((const char*)As + r * 128 + (koff ^ ((r & 7) << 4))); }
            { int r = wn * 64 + (l & 31);      b0 = *(const half8*)((const char*)Bs + r * 128 + (koff ^ ((r & 7) << 4))); }
            { int r = wn * 64 + 32 + (l & 31); b1 = *(const half8*)((const char*)Bs + r * 128 + (koff ^ ((r & 7) << 4))); }
            acc[0][0] = __builtin_amdgcn_mfma_f32_32x32x16_f16(a0, b0, acc[0][0], 0, 0, 0);
            acc[0][1] = __builtin_amdgcn_mfma_f32_32x32x16_f16(a0, b1, acc[0][1], 0, 0, 0);
            acc[1][0] = __builtin_amdgcn_mfma_f32_32x32x16_f16(a1, b0, acc[1][0], 0, 0, 0);
            acc[1][1] = __builtin_amdgcn_mfma_f32_32x32x16_f16(a1, b1, acc[1][1], 0, 0, 0);
        }
    }

#pragma unroll
    for (int mf = 0; mf < 2; ++mf) {
#pragma unroll
        for (int nf = 0; nf < 2; ++nf) {
            const int col = col0 + wn * 64 + nf * 32 + (l & 31);
            const float bc = HAS_BIAS ? bias[col] : 0.0f;
#pragma unroll
            for (int r = 0; r < 16; ++r) {
                int row = wm * 64 + mf * 32 + 4 * (l >> 5) + (r & 3) + 8 * (r >> 2);
                int g = row0 + row;
                if (g < nrows) {
                    float v = acc[mf][nf][r];
                    if (HAS_BIAS) v += (HAS_DEG ? (float)deg[g] : 1.0f) * bc;
                    if (RELU) v = fmaxf(v, 0.0f);
                    Out[(size_t)g * ldo + col] = (OutT)v;
                }
            }
        }
    }
}

// ---------------- MP edge pass over PQ[N,256] fp16, 8 nodes/block, 32 lanes x half4 ----------------
__global__ __launch_bounds__(256) void k_edge_mp(_Float16* __restrict__ PQ,
                                                 const int* __restrict__ offsets,
                                                 const int* __restrict__ csrc) {
    const int t = threadIdx.x;
    const int n = blockIdx.x * 8 + (t >> 5);
    if (n >= NN) return;
    const int lane = t & 31;
    const int beg = offsets[n], end = offsets[n + 1];
    half4 p4 = *(const half4*)(PQ + (size_t)n * 256 + lane * 4);
    const float p0 = (float)p4.x, p1 = (float)p4.y, p2 = (float)p4.z, p3 = (float)p4.w;
    float a0 = 0.f, a1 = 0.f, a2 = 0.f, a3 = 0.f;
    int i = beg;
#define LRELU4(vx, vy, vz, vw)                                        \
    a0 += ((vx) > 0.f) ? (vx) : 0.2f * (vx);                          \
    a1 += ((vy) > 0.f) ? (vy) : 0.2f * (vy);                          \
    a2 += ((vz) > 0.f) ? (vz) : 0.2f * (vz);                          \
    a3 += ((vw) > 0.f) ? (vw) : 0.2f * (vw);
    for (; i + 4 <= end; i += 4) {
        int s0 = csrc[i + 0], s1 = csrc[i + 1], s2 = csrc[i + 2], s3 = csrc[i + 3];
        half4 q0 = *(const half4*)(PQ + (size_t)s0 * 256 + 128 + lane * 4);
        half4 q1 = *(const half4*)(PQ + (size_t)s1 * 256 + 128 + lane * 4);
        half4 q2 = *(const half4*)(PQ + (size_t)s2 * 256 + 128 + lane * 4);
        half4 q3 = *(const half4*)(PQ + (size_t)s3 * 256 + 128 + lane * 4);
        LRELU4(p0 + (float)q0.x, p1 + (float)q0.y, p2 + (float)q0.z, p3 + (float)q0.w)
        LRELU4(p0 + (float)q1.x, p1 + (float)q1.y, p2 + (float)q1.z, p3 + (float)q1.w)
        LRELU4(p0 + (float)q2.x, p1 + (float)q2.y, p2 + (float)q2.z, p3 + (float)q2.w)
        LRELU4(p0 + (float)q3.x, p1 + (float)q3.y, p2 + (float)q3.z, p3 + (float)q3.w)
    }
    for (; i < end; ++i) {
        int s = csrc[i];
        half4 q = *(const half4*)(PQ + (size_t)s * 256 + 128 + lane * 4);
        LRELU4(p0 + (float)q.x, p1 + (float)q.y, p2 + (float)q.z, p3 + (float)q.w)
    }
#undef LRELU4
    half4 o;
    o.x = (_Float16)a0; o.y = (_Float16)a1; o.z = (_Float16)a2; o.w = (_Float16)a3;
    *(half4*)(PQ + (size_t)n * 256 + lane * 4) = o;
}

// ---------------- SpMM, 8 nodes/block (32 lanes x half4), X4 stride 512 ----------------
__global__ __launch_bounds__(256) void k_spmm(const _Float16* __restrict__ Xin,
                                              _Float16* __restrict__ Yout,
                                              const int* __restrict__ offsets,
                                              const int* __restrict__ csrc,
                                              const float* __restrict__ dinv) {
    const int t = threadIdx.x;
    const int n = blockIdx.x * 8 + (t >> 5);
    if (n >= NN) return;
    const int lane = t & 31;
    const int beg = offsets[n], end = offsets[n + 1];
    const float dn = dinv[n];
    float a0 = 0.f, a1 = 0.f, a2 = 0.f, a3 = 0.f;
    int i = beg;
    for (; i + 4 <= end; i += 4) {
        int s0 = csrc[i + 0], s1 = csrc[i + 1], s2 = csrc[i + 2], s3 = csrc[i + 3];
        float n0 = dinv[s0], n1 = dinv[s1], n2 = dinv[s2], n3 = dinv[s3];
        half4 v0 = *(const half4*)(Xin + (size_t)s0 * 512 + lane * 4);
        half4 v1 = *(const half4*)(Xin + (size_t)s1 * 512 + lane * 4);
        half4 v2 = *(const half4*)(Xin + (size_t)s2 * 512 + lane * 4);
        half4 v3 = *(const half4*)(Xin + (size_t)s3 * 512 + lane * 4);
        a0 += n0 * (float)v0.x + n1 * (float)v1.x + n2 * (float)v2.x + n3 * (float)v3.x;
        a1 += n0 * (float)v0.y + n1 * (float)v1.y + n2 * (float)v2.y + n3 * (float)v3.y;
        a2 += n0 * (float)v0.z + n1 * (float)v1.z + n2 * (float)v2.z + n3 * (float)v3.z;
        a3 += n0 * (float)v0.w + n1 * (float)v1.w + n2 * (float)v2.w + n3 * (float)v3.w;
    }
    for (; i < end; ++i) {
        int s = csrc[i];
        float nv = dinv[s];
        half4 v = *(const half4*)(Xin + (size_t)s * 512 + lane * 4);
        a0 += nv * (float)v.x; a1 += nv * (float)v.y;
        a2 += nv * (float)v.z; a3 += nv * (float)v.w;
    }
    half4 o;
    o.x = (_Float16)(dn * a0); o.y = (_Float16)(dn * a1);
    o.z = (_Float16)(dn * a2); o.w = (_Float16)(dn * a3);
    *(half4*)(Yout + (size_t)n * 512 + lane * 4) = o;
}

extern "C" void kernel_launch(void* const* d_in, const int* in_sizes, int n_in,
                              void* d_out, int out_size, void* d_ws, size_t ws_size,
                              hipStream_t stream) {
    const float* x  = (const float*)d_in[0];
    const int*   ei = (const int*)d_in[1];
    const float* W1 = (const float*)d_in[2];
    const float* b1 = (const float*)d_in[3];
    const float* W2 = (const float*)d_in[4];
    const float* b2 = (const float*)d_in[5];
    const float* tw = (const float*)d_in[6];
    const float* tb = (const float*)d_in[7];
    float* out = (float*)d_out;

    const int* srcp = ei;
    const int* dstp = ei + NE;

    char* p = (char*)d_ws;
    auto alloc = [&](size_t bytes) { char* r = p; p += align256(bytes); return r; };
    int*       deg     = (int*)alloc((size_t)NN * 4);
    int*       cursor  = (int*)alloc((size_t)NN * 4);
    int*       offsets = (int*)alloc((size_t)(NN + 1) * 4);
    float*     dinv    = (float*)alloc((size_t)NN * 4);
    int*       part    = (int*)alloc((size_t)NBLK * 4);
    int*       partoff = (int*)alloc((size_t)NBLK * 4);
    int*       csrc    = (int*)alloc((size_t)NE * 4);
    _Float16*  xh      = (_Float16*)alloc((size_t)NN * HH * 2);
    _Float16*  PQ      = (_Float16*)alloc((size_t)NN * 256 * 2);
    _Float16*  X4      = (_Float16*)alloc((size_t)NN * 512 * 2);
    _Float16*  W1t256  = (_Float16*)alloc((size_t)256 * 128 * 2);
    float*     bias256 = (float*)alloc(256 * 4);
    _Float16*  W2t     = (_Float16*)alloc(16384 * 2);
    _Float16*  TWt     = (_Float16*)alloc((size_t)3 * 65536 * 2);

    // k_cvt_w also zeros deg/cursor (tail threads)
    const int cvtw_work = 49152 + 3 * 65536 + 256 + NN;
    k_cvt_w<<<(cvtw_work + 255) / 256, 256, 0, stream>>>(W1, W2, tw, b1, W1t256, bias256,
                                                         W2t, TWt, deg, cursor);
    k_cvt_x<<<(NN * HH / 4 + 255) / 256, 256, 0, stream>>>(x, xh);

    k_deg<<<8 * TSB, 256, 0, stream>>>(dstp, deg);
    k_bsum<<<NBLK, SCAN_BLK, 0, stream>>>(deg, part);
    k_scanpart<<<1, SCAN_BLK, 0, stream>>>(part, partoff);
    k_apply<<<NBLK, SCAN_BLK, 0, stream>>>(deg, partoff, offsets, dinv);
    k_fill<<<8 * TSB, 256, 0, stream>>>(srcp, dstp, offsets, cursor, csrc);

    const int mmgrid = (NN + 127) / 128;

    // MP layer: PQ = x @ [W1P|W1Q] + [b1|0]  (single fused GEMM, 2 col-tiles)
    k_mm<128, 1, 0, 0, _Float16><<<dim3(mmgrid, 2), 256, 0, stream>>>(
        xh, HH, W1t256, bias256, nullptr, PQ, 256, NN);
    k_edge_mp<<<NB8, 256, 0, stream>>>(PQ, offsets, csrc);
    k_mm<128, 1, 1, 0, _Float16><<<dim3(mmgrid, 1), 256, 0, stream>>>(
        PQ, 256, W2t, b2, deg, X4, 512, NN);

    // 3 TAGConv layers
    for (int L = 0; L < 3; ++L) {
        const _Float16* Wt = TWt + (size_t)L * 65536;
        const float* bL = tb + (size_t)L * 128;
        k_spmm<<<NB8, 256, 0, stream>>>(X4 + 0,   X4 + 128, offsets, csrc, dinv);
        k_spmm<<<NB8, 256, 0, stream>>>(X4 + 128, X4 + 256, offsets, csrc, dinv);
        k_spmm<<<NB8, 256, 0, stream>>>(X4 + 256, X4 + 384, offsets, csrc, dinv);
        if (L < 2) {
            k_mm<512, 1, 0, 1, _Float16><<<dim3(mmgrid, 1), 256, 0, stream>>>(
                X4, 512, Wt, bL, nullptr, X4, 512, NN);
        } else {
            k_mm<512, 1, 0, 1, float><<<dim3(mmgrid, 1), 256, 0, stream>>>(
                X4, 512, Wt, bL, nullptr, out, HH, NN);
        }
    }
}

// Round 12
// 518.625 us; speedup vs baseline: 1.0187x; 1.0187x over previous
//
#include <hip/hip_runtime.h>

#define NN 50000
#define NE 800000
#define HH 128
#define SCAN_BLK 256
#define NBLK ((NN + SCAN_BLK - 1) / SCAN_BLK)   // 196
#define NB8 ((NN + 7) / 8)                      // 6250 (8 nodes/block)
#define NPT 6250                                // nodes per XCD team
#define TSB 128                                 // stripes per team
#define ECH ((NE + TSB - 1) / TSB)              // edges per stripe

typedef _Float16 half8 __attribute__((ext_vector_type(8)));
typedef _Float16 half4 __attribute__((ext_vector_type(4)));
typedef float floatx16 __attribute__((ext_vector_type(16)));

static inline size_t align256(size_t x) { return (x + 255) & ~(size_t)255; }

// ---------------- degree histogram, XCD-pinned teams ----------------
__global__ __launch_bounds__(256) void k_deg(const int* __restrict__ dst,
                                             int* __restrict__ deg) {
    const int c = blockIdx.x & 7;
    const int stripe = blockIdx.x >> 3;
    const int lo = c * NPT, hi = min(NN, lo + NPT);
    const int e0 = stripe * ECH;
    const int e1 = min(NE, e0 + ECH);
    for (int e = e0 + threadIdx.x; e < e1; e += 256) {
        int d = __builtin_nontemporal_load(dst + e);
        if (d >= lo && d < hi) atomicAdd(&deg[d], 1);
    }
}

// ---------------- two-level scan ----------------
__global__ void k_bsum(const int* __restrict__ deg, int* __restrict__ part) {
    __shared__ int sd[SCAN_BLK];
    int t = threadIdx.x;
    int i = blockIdx.x * SCAN_BLK + t;
    sd[t] = (i < NN) ? deg[i] : 0;
    __syncthreads();
    for (int off = SCAN_BLK / 2; off > 0; off >>= 1) {
        if (t < off) sd[t] += sd[t + off];
        __syncthreads();
    }
    if (t == 0) part[blockIdx.x] = sd[0];
}

__global__ void k_scanpart(const int* __restrict__ part, int* __restrict__ partoff) {
    __shared__ int sd[SCAN_BLK];
    int t = threadIdx.x;
    int v = (t < NBLK) ? part[t] : 0;
    sd[t] = v;
    __syncthreads();
    for (int off = 1; off < SCAN_BLK; off <<= 1) {
        int add = (t >= off) ? sd[t - off] : 0;
        __syncthreads();
        sd[t] += add;
        __syncthreads();
    }
    if (t < NBLK) partoff[t] = sd[t] - v;
}

__global__ void k_apply(const int* __restrict__ deg, const int* __restrict__ partoff,
                        int* __restrict__ offsets, float* __restrict__ dinv) {
    __shared__ int sd[SCAN_BLK];
    int t = threadIdx.x;
    int i = blockIdx.x * SCAN_BLK + t;
    int v = (i < NN) ? deg[i] : 0;
    sd[t] = v;
    __syncthreads();
    for (int off = 1; off < SCAN_BLK; off <<= 1) {
        int add = (t >= off) ? sd[t - off] : 0;
        __syncthreads();
        sd[t] += add;
        __syncthreads();
    }
    if (i < NN) {
        offsets[i] = partoff[blockIdx.x] + sd[t] - v;
        dinv[i] = (v > 0) ? rsqrtf((float)v) : 0.0f;
    }
    if (i == 0) offsets[NN] = NE;
}

// ---------------- CSR fill, XCD-pinned teams ----------------
__global__ __launch_bounds__(256) void k_fill(const int* __restrict__ src,
                                              const int* __restrict__ dst,
                                              const int* __restrict__ offsets,
                                              int* __restrict__ cursor,
                                              int* __restrict__ csrc) {
    const int c = blockIdx.x & 7;
    const int stripe = blockIdx.x >> 3;
    const int lo = c * NPT, hi = min(NN, lo + NPT);
    const int e0 = stripe * ECH;
    const int e1 = min(NE, e0 + ECH);
    for (int e = e0 + threadIdx.x; e < e1; e += 256) {
        int d = __builtin_nontemporal_load(dst + e);
        if (d >= lo && d < hi) {
            int s = __builtin_nontemporal_load(src + e);
            int pos = atomicAdd(&cursor[d], 1);
            csrc[offsets[d] + pos] = s;
        }
    }
}

// ---------------- convert + transpose weights to fp16 k-major (+ zero deg/cursor) ----------------
__global__ void k_cvt_w(const float* __restrict__ W1, const float* __restrict__ W2,
                        const float* __restrict__ tw, const float* __restrict__ b1,
                        _Float16* __restrict__ W1t256, float* __restrict__ bias256,
                        _Float16* __restrict__ W2t, _Float16* __restrict__ TWt,
                        int* __restrict__ deg, int* __restrict__ cursor) {
    int i = blockIdx.x * 256 + threadIdx.x;
    if (i < 32768) {
        int c = i >> 7, k = i & 127;
        W1t256[c * 128 + k] = (c < 128) ? (_Float16)W1[k * 128 + c]
                                        : (_Float16)W1[(128 + k) * 128 + (c - 128)];
    } else if (i < 49152) {
        int j = i - 32768;
        int c = j >> 7, k = j & 127;
        W2t[c * 128 + k] = (_Float16)W2[k * 128 + c];
    } else if (i < 49152 + 3 * 65536) {
        int j = i - 49152;
        int L = j >> 16;
        int c = (j >> 9) & 127;
        int k = j & 511;
        TWt[(size_t)L * 65536 + c * 512 + k] =
            (_Float16)tw[(size_t)L * 65536 + (size_t)(k >> 7) * 16384 + (size_t)(k & 127) * 128 + c];
    } else {
        int j = i - (49152 + 3 * 65536);
        if (j < 256) bias256[j] = (j < 128) ? b1[j] : 0.0f;
        int z = j - 256;
        if (z >= 0 && z < NN) { deg[z] = 0; cursor[z] = 0; }
    }
}

// ---------------- MFMA GEMM (col-tiled via blockIdx.y; AF32 = fp32 A with on-the-fly cvt) ----------------
template <int KDIM, int AF32, int HAS_BIAS, int HAS_DEG, int RELU, typename OutT>
__global__ __launch_bounds__(256) void k_mm(
    const void* __restrict__ Avoid, int lda,
    const _Float16* __restrict__ Bt,
    const float* __restrict__ bias, const int* __restrict__ deg,
    OutT* __restrict__ Out, int ldo, int nrows) {
    __shared__ _Float16 As[128 * 64];
    __shared__ _Float16 Bs[128 * 64];
    const int t = threadIdx.x;
    const int l = t & 63;
    const int w = t >> 6;
    const int wm = w >> 1, wn = w & 1;
    const int row0 = blockIdx.x * 128;
    const int col0 = blockIdx.y * 128;
    const _Float16* BtT = Bt + (size_t)col0 * KDIM;

    floatx16 acc[2][2] = {};

    const int srow = t >> 3;
    const int sslot = t & 7;

    for (int c = 0; c < KDIM / 64; ++c) {
        __syncthreads();
#pragma unroll
        for (int p = 0; p < 4; ++p) {
            int r = srow + p * 32;
            int g = row0 + r;
            uint4 v = make_uint4(0, 0, 0, 0);
            if (g < nrows) {
                if (AF32) {
                    const float* Af = (const float*)Avoid;
                    const float4 f0 = *(const float4*)(Af + (size_t)g * lda + c * 64 + sslot * 8);
                    const float4 f1 = *(const float4*)(Af + (size_t)g * lda + c * 64 + sslot * 8 + 4);
                    half8 h;
                    h[0] = (_Float16)f0.x; h[1] = (_Float16)f0.y;
                    h[2] = (_Float16)f0.z; h[3] = (_Float16)f0.w;
                    h[4] = (_Float16)f1.x; h[5] = (_Float16)f1.y;
                    h[6] = (_Float16)f1.z; h[7] = (_Float16)f1.w;
                    v = *(const uint4*)&h;
                } else {
                    const _Float16* Ah = (const _Float16*)Avoid;
                    v = *(const uint4*)(Ah + (size_t)g * lda + c * 64 + sslot * 8);
                }
            }
            *(uint4*)((char*)As + r * 128 + ((sslot * 16) ^ ((r & 7) << 4))) = v;
        }
#pragma unroll
        for (int p = 0; p < 4; ++p) {
            int r = srow + p * 32;
            uint4 v = *(const uint4*)(BtT + (size_t)r * KDIM + c * 64 + sslot * 8);
            *(uint4*)((char*)Bs + r * 128 + ((sslot * 16) ^ ((r & 7) << 4))) = v;
        }
        __syncthreads();
#pragma unroll
        for (int ks = 0; ks < 4; ++ks) {
            const int koff = ks * 32 + (l >> 5) * 16;
            half8 a0, a1, b0, b1;
            { int r = wm * 64 + (l & 31);      a0 = *(const half8*)((const char*)As + r * 128 + (koff ^ ((r & 7) << 4))); }
            { int r = wm * 64 + 32 + (l & 31); a1 = *(const half8*)((const char*)As + r * 128 + (koff ^ ((r & 7) << 4))); }
            { int r = wn * 64 + (l & 31);      b0 = *(const half8*)((const char*)Bs + r * 128 + (koff ^ ((r & 7) << 4))); }
            { int r = wn * 64 + 32 + (l & 31); b1 = *(const half8*)((const char*)Bs + r * 128 + (koff ^ ((r & 7) << 4))); }
            acc[0][0] = __builtin_amdgcn_mfma_f32_32x32x16_f16(a0, b0, acc[0][0], 0, 0, 0);
            acc[0][1] = __builtin_amdgcn_mfma_f32_32x32x16_f16(a0, b1, acc[0][1], 0, 0, 0);
            acc[1][0] = __builtin_amdgcn_mfma_f32_32x32x16_f16(a1, b0, acc[1][0], 0, 0, 0);
            acc[1][1] = __builtin_amdgcn_mfma_f32_32x32x16_f16(a1, b1, acc[1][1], 0, 0, 0);
        }
    }

#pragma unroll
    for (int mf = 0; mf < 2; ++mf) {
#pragma unroll
        for (int nf = 0; nf < 2; ++nf) {
            const int col = col0 + wn * 64 + nf * 32 + (l & 31);
            const float bc = HAS_BIAS ? bias[col] : 0.0f;
#pragma unroll
            for (int r = 0; r < 16; ++r) {
                int row = wm * 64 + mf * 32 + 4 * (l >> 5) + (r & 3) + 8 * (r >> 2);
                int g = row0 + row;
                if (g < nrows) {
                    float v = acc[mf][nf][r];
                    if (HAS_BIAS) v += (HAS_DEG ? (float)deg[g] : 1.0f) * bc;
                    if (RELU) v = fmaxf(v, 0.0f);
                    Out[(size_t)g * ldo + col] = (OutT)v;
                }
            }
        }
    }
}

// ---------------- MP edge pass over PQ[N,256] fp16, 8 nodes/block, 32 lanes x half4 ----------------
__global__ __launch_bounds__(256) void k_edge_mp(_Float16* __restrict__ PQ,
                                                 const int* __restrict__ offsets,
                                                 const int* __restrict__ csrc) {
    const int t = threadIdx.x;
    const int n = blockIdx.x * 8 + (t >> 5);
    if (n >= NN) return;
    const int lane = t & 31;
    const int beg = offsets[n], end = offsets[n + 1];
    half4 p4 = *(const half4*)(PQ + (size_t)n * 256 + lane * 4);
    const float p0 = (float)p4.x, p1 = (float)p4.y, p2 = (float)p4.z, p3 = (float)p4.w;
    float a0 = 0.f, a1 = 0.f, a2 = 0.f, a3 = 0.f;
    int i = beg;
#define LRELU4(vx, vy, vz, vw)                                        \
    a0 += ((vx) > 0.f) ? (vx) : 0.2f * (vx);                          \
    a1 += ((vy) > 0.f) ? (vy) : 0.2f * (vy);                          \
    a2 += ((vz) > 0.f) ? (vz) : 0.2f * (vz);                          \
    a3 += ((vw) > 0.f) ? (vw) : 0.2f * (vw);
    for (; i + 4 <= end; i += 4) {
        int s0 = csrc[i + 0], s1 = csrc[i + 1], s2 = csrc[i + 2], s3 = csrc[i + 3];
        half4 q0 = *(const half4*)(PQ + (size_t)s0 * 256 + 128 + lane * 4);
        half4 q1 = *(const half4*)(PQ + (size_t)s1 * 256 + 128 + lane * 4);
        half4 q2 = *(const half4*)(PQ + (size_t)s2 * 256 + 128 + lane * 4);
        half4 q3 = *(const half4*)(PQ + (size_t)s3 * 256 + 128 + lane * 4);
        LRELU4(p0 + (float)q0.x, p1 + (float)q0.y, p2 + (float)q0.z, p3 + (float)q0.w)
        LRELU4(p0 + (float)q1.x, p1 + (float)q1.y, p2 + (float)q1.z, p3 + (float)q1.w)
        LRELU4(p0 + (float)q2.x, p1 + (float)q2.y, p2 + (float)q2.z, p3 + (float)q2.w)
        LRELU4(p0 + (float)q3.x, p1 + (float)q3.y, p2 + (float)q3.z, p3 + (float)q3.w)
    }
    for (; i < end; ++i) {
        int s = csrc[i];
        half4 q = *(const half4*)(PQ + (size_t)s * 256 + 128 + lane * 4);
        LRELU4(p0 + (float)q.x, p1 + (float)q.y, p2 + (float)q.z, p3 + (float)q.w)
    }
#undef LRELU4
    half4 o;
    o.x = (_Float16)a0; o.y = (_Float16)a1; o.z = (_Float16)a2; o.w = (_Float16)a3;
    *(half4*)(PQ + (size_t)n * 256 + lane * 4) = o;
}

// ---------------- SpMM, 8 nodes/block (32 lanes x half4), X4 stride 512 ----------------
__global__ __launch_bounds__(256) void k_spmm(const _Float16* __restrict__ Xin,
                                              _Float16* __restrict__ Yout,
                                              const int* __restrict__ offsets,
                                              const int* __restrict__ csrc,
                                              const float* __restrict__ dinv) {
    const int t = threadIdx.x;
    const int n = blockIdx.x * 8 + (t >> 5);
    if (n >= NN) return;
    const int lane = t & 31;
    const int beg = offsets[n], end = offsets[n + 1];
    const float dn = dinv[n];
    float a0 = 0.f, a1 = 0.f, a2 = 0.f, a3 = 0.f;
    int i = beg;
    for (; i + 4 <= end; i += 4) {
        int s0 = csrc[i + 0], s1 = csrc[i + 1], s2 = csrc[i + 2], s3 = csrc[i + 3];
        float n0 = dinv[s0], n1 = dinv[s1], n2 = dinv[s2], n3 = dinv[s3];
        half4 v0 = *(const half4*)(Xin + (size_t)s0 * 512 + lane * 4);
        half4 v1 = *(const half4*)(Xin + (size_t)s1 * 512 + lane * 4);
        half4 v2 = *(const half4*)(Xin + (size_t)s2 * 512 + lane * 4);
        half4 v3 = *(const half4*)(Xin + (size_t)s3 * 512 + lane * 4);
        a0 += n0 * (float)v0.x + n1 * (float)v1.x + n2 * (float)v2.x + n3 * (float)v3.x;
        a1 += n0 * (float)v0.y + n1 * (float)v1.y + n2 * (float)v2.y + n3 * (float)v3.y;
        a2 += n0 * (float)v0.z + n1 * (float)v1.z + n2 * (float)v2.z + n3 * (float)v3.z;
        a3 += n0 * (float)v0.w + n1 * (float)v1.w + n2 * (float)v2.w + n3 * (float)v3.w;
    }
    for (; i < end; ++i) {
        int s = csrc[i];
        float nv = dinv[s];
        half4 v = *(const half4*)(Xin + (size_t)s * 512 + lane * 4);
        a0 += nv * (float)v.x; a1 += nv * (float)v.y;
        a2 += nv * (float)v.z; a3 += nv * (float)v.w;
    }
    half4 o;
    o.x = (_Float16)(dn * a0); o.y = (_Float16)(dn * a1);
    o.z = (_Float16)(dn * a2); o.w = (_Float16)(dn * a3);
    *(half4*)(Yout + (size_t)n * 512 + lane * 4) = o;
}

extern "C" void kernel_launch(void* const* d_in, const int* in_sizes, int n_in,
                              void* d_out, int out_size, void* d_ws, size_t ws_size,
                              hipStream_t stream) {
    const float* x  = (const float*)d_in[0];
    const int*   ei = (const int*)d_in[1];
    const float* W1 = (const float*)d_in[2];
    const float* b1 = (const float*)d_in[3];
    const float* W2 = (const float*)d_in[4];
    const float* b2 = (const float*)d_in[5];
    const float* tw = (const float*)d_in[6];
    const float* tb = (const float*)d_in[7];
    float* out = (float*)d_out;

    const int* srcp = ei;
    const int* dstp = ei + NE;

    char* p = (char*)d_ws;
    auto alloc = [&](size_t bytes) { char* r = p; p += align256(bytes); return r; };
    int*       deg     = (int*)alloc((size_t)NN * 4);
    int*       cursor  = (int*)alloc((size_t)NN * 4);
    int*       offsets = (int*)alloc((size_t)(NN + 1) * 4);
    float*     dinv    = (float*)alloc((size_t)NN * 4);
    int*       part    = (int*)alloc((size_t)NBLK * 4);
    int*       partoff = (int*)alloc((size_t)NBLK * 4);
    int*       csrc    = (int*)alloc((size_t)NE * 4);
    _Float16*  PQ      = (_Float16*)alloc((size_t)NN * 256 * 2);
    _Float16*  X4      = (_Float16*)alloc((size_t)NN * 512 * 2);
    _Float16*  W1t256  = (_Float16*)alloc((size_t)256 * 128 * 2);
    float*     bias256 = (float*)alloc(256 * 4);
    _Float16*  W2t     = (_Float16*)alloc(16384 * 2);
    _Float16*  TWt     = (_Float16*)alloc((size_t)3 * 65536 * 2);

    // k_cvt_w also zeros deg/cursor (tail threads)
    const int cvtw_work = 49152 + 3 * 65536 + 256 + NN;
    k_cvt_w<<<(cvtw_work + 255) / 256, 256, 0, stream>>>(W1, W2, tw, b1, W1t256, bias256,
                                                         W2t, TWt, deg, cursor);

    k_deg<<<8 * TSB, 256, 0, stream>>>(dstp, deg);
    k_bsum<<<NBLK, SCAN_BLK, 0, stream>>>(deg, part);
    k_scanpart<<<1, SCAN_BLK, 0, stream>>>(part, partoff);
    k_apply<<<NBLK, SCAN_BLK, 0, stream>>>(deg, partoff, offsets, dinv);
    k_fill<<<8 * TSB, 256, 0, stream>>>(srcp, dstp, offsets, cursor, csrc);

    const int mmgrid = (NN + 127) / 128;

    // MP layer: PQ = x @ [W1P|W1Q] + [b1|0]  (fp32 A read + on-the-fly cvt, 2 col-tiles)
    k_mm<128, 1, 1, 0, 0, _Float16><<<dim3(mmgrid, 2), 256, 0, stream>>>(
        x, HH, W1t256, bias256, nullptr, PQ, 256, NN);
    k_edge_mp<<<NB8, 256, 0, stream>>>(PQ, offsets, csrc);
    k_mm<128, 0, 1, 1, 0, _Float16><<<dim3(mmgrid, 1), 256, 0, stream>>>(
        PQ, 256, W2t, b2, deg, X4, 512, NN);

    // 3 TAGConv layers
    for (int L = 0; L < 3; ++L) {
        const _Float16* Wt = TWt + (size_t)L * 65536;
        const float* bL = tb + (size_t)L * 128;
        k_spmm<<<NB8, 256, 0, stream>>>(X4 + 0,   X4 + 128, offsets, csrc, dinv);
        k_spmm<<<NB8, 256, 0, stream>>>(X4 + 128, X4 + 256, offsets, csrc, dinv);
        k_spmm<<<NB8, 256, 0, stream>>>(X4 + 256, X4 + 384, offsets, csrc, dinv);
        if (L < 2) {
            k_mm<512, 0, 1, 0, 1, _Float16><<<dim3(mmgrid, 1), 256, 0, stream>>>(
                X4, 512, Wt, bL, nullptr, X4, 512, NN);
        } else {
            k_mm<512, 0, 1, 0, 1, float><<<dim3(mmgrid, 1), 256, 0, stream>>>(
                X4, 512, Wt, bL, nullptr, out, HH, NN);
        }
    }
}